// Round 24
// baseline (146.699 us; speedup 1.0000x reference)
//
#include <hip/hip_runtime.h>
#include <math.h>

#define N_PTS 512
#define HID 128
#define KNN 8
#define MT 16               // m-tile per block
#define NTHREADS 256        // 4 waves
#define NROWS 144           // 16 d rows + 128 a rows (8k x 16m)

typedef __attribute__((ext_vector_type(8))) short short8_t;    // 8 bf16 (4 VGPRs)
typedef __attribute__((ext_vector_type(4))) float f32x4_t;     // 16x16 MFMA acc
typedef __attribute__((ext_vector_type(16))) float f32x16_t;   // 32x32 MFMA acc

// Persistent scratch in static device globals.
__device__ float g_refv[N_PTS * KNN * 3];            // [n][k][xyz] neighbor ref vectors
__device__ unsigned short g_wfrag[2 * 8 * 4 * 64 * 8];   // 16x16 B-frags (Wd used)
__device__ unsigned short g_wfrag32[4 * 8 * 64 * 8];     // Wa 32x32 B-frags [gg][kc][lane][j]

__device__ __forceinline__ unsigned short f2bf(float f) {   // RNE f32->bf16
    const unsigned int u = __float_as_uint(f);
    return (unsigned short)((u + 0x7FFFu + ((u >> 16) & 1u)) >> 16);
}

// -------- prep: fused wave-kNN + wfrag (r18/r19/r22-PASS) + wfrag32 ---------
__global__ void __launch_bounds__(64) prep_kernel(
    const float* __restrict__ points, const float* __restrict__ Wd,
    const float* __restrict__ Wa)
{
    __shared__ float spts[N_PTS * 3];
    const int lane = threadIdx.x;       // 0..63
    const int n = blockIdx.x;           // 0..511

    for (int i = lane; i < N_PTS * 3; i += 64) spts[i] = points[i];
    __syncthreads();

    // ---- 16x16 weight fragments (Wd path) ----
    {
        const int idx = n * 64 + lane;
        const int sel = idx >> 14;          // 0 = Wd, 1 = Wa
        const int rem = idx & 16383;
        const int gg = rem >> 7, kk = rem & 127;
        const int gtile = gg >> 4, glo = gg & 15;
        const int ktile = kk >> 5, kmid = (kk >> 3) & 3, j = kk & 7;
        const int fl = kmid * 16 + glo;
        const int dst = ((((sel * 8 + gtile) * 4 + ktile) * 64) + fl) * 8 + j;
        const float v = sel ? Wa[gg * HID + kk] : Wd[gg * HID + kk];
        g_wfrag[dst] = f2bf(v);
    }
    // ---- Wa 32x32 B-frags: col=lane&31 (g), k = kchunk*16 + (lane>>5)*8 + j --
    if (lane < 32) {
        const int idx = n * 32 + lane;      // 0..16383
        const int gg = idx >> 7, kk = idx & 127;
        const int ggroup = gg >> 5, c = gg & 31;
        const int kchunk = kk >> 4, hi2 = (kk >> 3) & 1, j = kk & 7;
        const int fl = hi2 * 32 + c;
        const int dst = ((ggroup * 8 + kchunk) * 64 + fl) * 8 + j;
        g_wfrag32[dst] = f2bf(Wa[gg * HID + kk]);
    }

    // ---- kNN: 8 candidates per lane, 9 shfl-min rounds ----
    const float px = spts[n * 3 + 0], py = spts[n * 3 + 1], pz = spts[n * 3 + 2];
    unsigned long long keys[8];
#pragma unroll
    for (int j = 0; j < 8; ++j) {
        const int m = lane * 8 + j;
        const float dx = spts[m * 3 + 0] - px;
        const float dy = spts[m * 3 + 1] - py;
        const float dz = spts[m * 3 + 2] - pz;
        const float sq = dx * dx + dy * dy + dz * dz;
        keys[j] = ((unsigned long long)__float_as_uint(sq) << 32) | (unsigned)m;
    }
    for (int r = 0; r < 9; ++r) {
        unsigned long long lmin = ~0ULL;
#pragma unroll
        for (int j = 0; j < 8; ++j) lmin = keys[j] < lmin ? keys[j] : lmin;
        for (int s = 1; s < 64; s <<= 1) {
            const unsigned long long o = __shfl_xor(lmin, s, 64);
            lmin = o < lmin ? o : lmin;
        }
        const int mwin = (int)(unsigned)lmin;
        if ((mwin >> 3) == lane) keys[mwin & 7] = ~0ULL;
        if (r > 0 && lane == 0) {
            const int k = r - 1;
            g_refv[(n * KNN + k) * 3 + 0] = __fsub_rn(spts[mwin * 3 + 0], px);
            g_refv[(n * KNN + k) * 3 + 1] = __fsub_rn(spts[mwin * 3 + 1], py);
            g_refv[(n * KNN + k) * 3 + 2] = __fsub_rn(spts[mwin * 3 + 2], pz);
        }
    }
}

// -------- main: fill (r22 verbatim) + 32x32 a-GEMM (m-partition) + d 16x16 --
__global__ void __launch_bounds__(NTHREADS, 3) main_kernel(
    const float* __restrict__ points, const float* __restrict__ bd,
    const float* __restrict__ ba, float* __restrict__ out)
{
    __shared__ __align__(16) unsigned short sA[NROWS * HID];  // 36 KB, XOR-swizzled
    __shared__ __align__(16) float sOut[MT * HID];            // 8 KB a-part results
    __shared__ __align__(16) float sBaseS[4][36];
    __shared__ float sRef[KNN][3];
    __shared__ float sPm[MT][3];
    __shared__ float sPn[3];

    const int t = threadIdx.x;
    const int n = blockIdx.y;
    const int m0 = blockIdx.x * MT;

    const int r0 = t >> 6;              // wave id (0..3)
    const int i  = t & 63;              // lane / frequency index
    const float dv2 = expf(-0.14391156831212787f * (float)i) * 0.15915494309189535f;

    // ---- stage small data ----
    if (t < 3) sPn[t] = points[n * 3 + t];
    if (t >= 64 && t < 64 + MT * 3) { int q = t - 64;  sPm[q / 3][q % 3] = points[m0 * 3 + q]; }
    if (t >= 128 && t < 128 + KNN * 3) { int q = t - 128; sRef[q / 3][q % 3] = g_refv[n * KNN * 3 + q]; }
    __syncthreads();

    // ---- geometry (r12-validated arithmetic) ----
    if (t < MT) {
        const float qx = sPm[t][0], qy = sPm[t][1], qz = sPm[t][2];
        const float sn = __fadd_rn(__fadd_rn(__fmul_rn(sPn[0], sPn[0]), __fmul_rn(sPn[1], sPn[1])), __fmul_rn(sPn[2], sPn[2]));
        const float sm = __fadd_rn(__fadd_rn(__fmul_rn(qx, qx), __fmul_rn(qy, qy)), __fmul_rn(qz, qz));
        float dot = __fmul_rn(sPn[0], qx);
        dot = fmaf(sPn[1], qy, dot);
        dot = fmaf(sPn[2], qz, dot);
        float sq = __fsub_rn(__fadd_rn(sn, sm), __fadd_rn(dot, dot));
        sq = fmaxf(sq, 0.0f);
        sBaseS[t & 3][t >> 2] = __fdiv_rn(__fsqrt_rn(sq), 0.2f);
    }
    if (t < MT * KNN) {
        const int pair = t >> 3, k = t & 7;
        const float ax = sPm[pair][0] - sPn[0];
        const float ay = sPm[pair][1] - sPn[1];
        const float az = sPm[pair][2] - sPn[2];
        const float rx = sRef[k][0], ry = sRef[k][1], rz = sRef[k][2];
        const float cx = ry * az - rz * ay;
        const float cy = rz * ax - rx * az;
        const float cz = rx * ay - ry * ax;
        const float sv = sqrtf(cx * cx + cy * cy + cz * cz);
        const float cv = rx * ax + ry * ay + rz * az;
        float ang;
        if (sv == 0.0f) ang = 0.0f;          // degenerate -> 0, NEVER pi (r12 fix)
        else            ang = atan2f(sv, cv);
        sBaseS[pair & 3][4 + 4 * k + (pair >> 2)] = ang * 3.8197186342054885f;
    }
    __syncthreads();

    // ---- A tile fill (r22 verbatim values) ----
    {
        float rbase[36];
#pragma unroll
        for (int q = 0; q < 9; ++q) {
            const float4 v = *(const float4*)&sBaseS[r0][q * 4];
            rbase[q * 4 + 0] = v.x; rbase[q * 4 + 1] = v.y;
            rbase[q * 4 + 2] = v.z; rbase[q * 4 + 3] = v.w;
        }
        const unsigned base0 = (unsigned)((i * 4) ^ (r0 << 4)) + (unsigned)r0 * 256;
        char* const wr0 = (char*)sA + base0;
        char* const wr1 = (char*)sA + (base0 ^ 64u);
#pragma unroll
        for (int it = 0; it < 36; ++it) {
            const float rev0 = rbase[it] * dv2;
            const float rev  = rev0 - floorf(rev0);
            const float s = __builtin_amdgcn_sinf(rev);
            const float c = __builtin_amdgcn_cosf(rev);
            const unsigned int pack = __builtin_amdgcn_perm(
                __float_as_uint(c), __float_as_uint(s), 0x07060302u);
            char* const wp = (it & 1) ? wr1 : wr0;
            *(unsigned int*)(wp + it * 1024) = pack;
        }
    }
    __syncthreads();

    const int wid = r0, lane = i;
    const char* sAb = (const char*)sA;

    // ---- a-part: wave owns 4 m's (wid*4..+3) x all 128 g, 32x32x16 MFMA ----
    // A rows: lane&31 = r -> (k = r>>2, mm = r&3); row = 16 + k*16 + wid*4 + mm
    const int c31 = lane & 31;
    const int hi  = lane >> 5;
    const int arow = MT + (c31 >> 2) * 16 + wid * 4 + (c31 & 3);
    const int aswz = (arow & 7) << 4;
    short8_t afr[8];
#pragma unroll
    for (int kc = 0; kc < 8; ++kc) {
        const int byte = (arow * 256 + kc * 32 + hi * 16) ^ aswz;
        afr[kc] = *(const short8_t*)(sAb + byte);
    }
    const short8_t* wf32 = (const short8_t*)g_wfrag32;
#pragma unroll
    for (int half = 0; half < 2; ++half) {
        const int g0 = half * 2, g1 = half * 2 + 1;
        f32x16_t a0 = {0.f,0.f,0.f,0.f,0.f,0.f,0.f,0.f,0.f,0.f,0.f,0.f,0.f,0.f,0.f,0.f};
        f32x16_t a1 = {0.f,0.f,0.f,0.f,0.f,0.f,0.f,0.f,0.f,0.f,0.f,0.f,0.f,0.f,0.f,0.f};
#pragma unroll
        for (int kc = 0; kc < 8; ++kc) {
            a0 = __builtin_amdgcn_mfma_f32_32x32x16_bf16(afr[kc], wf32[(g0 * 8 + kc) * 64 + lane], a0, 0, 0, 0);
            a1 = __builtin_amdgcn_mfma_f32_32x32x16_bf16(afr[kc], wf32[(g1 * 8 + kc) * 64 + lane], a1, 0, 0, 0);
        }
        // C/D: col=lane&31, row=(reg&3)+8*(reg>>2)+4*hi -> m=reg&3, k=2*(reg>>2)+hi
#pragma unroll
        for (int m = 0; m < 4; ++m) {
            float v0 = fmaxf(fmaxf(a0[m], a0[m + 4]), fmaxf(a0[m + 8], a0[m + 12]));
            float v1 = fmaxf(fmaxf(a1[m], a1[m + 4]), fmaxf(a1[m + 8], a1[m + 12]));
            v0 = fmaxf(v0, __shfl_xor(v0, 32, 64));   // combine odd/even k halves
            v1 = fmaxf(v1, __shfl_xor(v1, 32, 64));
            if (hi == 0) {
                sOut[(wid * 4 + m) * HID + g0 * 32 + c31] = v0;
                sOut[(wid * 4 + m) * HID + g1 * 32 + c31] = v1;
            }
        }
    }

    // ---- d-part: 16x16x32, wave owns g-tiles {2w, 2w+1} (r22 verbatim) ----
    const int rlo  = lane & 15;
    const int kseg = lane >> 4;
    const short8_t* wf = (const short8_t*)g_wfrag;
    short8_t wdb[2][4];
#pragma unroll
    for (int gt = 0; gt < 2; ++gt) {
        const int gtile = wid * 2 + gt;
#pragma unroll
        for (int kt = 0; kt < 4; ++kt)
            wdb[gt][kt] = wf[(gtile * 4 + kt) * 64 + lane];
    }
    f32x4_t accd[2] = {{0.f,0.f,0.f,0.f}, {0.f,0.f,0.f,0.f}};
#pragma unroll
    for (int kt = 0; kt < 4; ++kt) {
        int byte = rlo * 256 + kt * 64 + kseg * 16;
        byte ^= (rlo & 7) << 4;
        const short8_t af = *(const short8_t*)(sAb + byte);
        accd[0] = __builtin_amdgcn_mfma_f32_16x16x32_bf16(af, wdb[0][kt], accd[0], 0, 0, 0);
        accd[1] = __builtin_amdgcn_mfma_f32_16x16x32_bf16(af, wdb[1][kt], accd[1], 0, 0, 0);
    }

    __syncthreads();   // sOut ready

    // ---- combine + store: col=lane&15 (g), row=(lane>>4)*4+reg (m) ----
#pragma unroll
    for (int gt = 0; gt < 2; ++gt) {
        const int g = (wid * 2 + gt) * 16 + rlo;
        const float bdv = bd[g];
        const float bav = ba[g];
#pragma unroll
        for (int r = 0; r < 4; ++r) {
            const int m = kseg * 4 + r;
            out[(n * N_PTS + (m0 + m)) * HID + g] = accd[gt][r] + bdv + sOut[m * HID + g] + bav;
        }
    }
}

extern "C" void kernel_launch(void* const* d_in, const int* in_sizes, int n_in,
                              void* d_out, int out_size, void* d_ws, size_t ws_size,
                              hipStream_t stream) {
    (void)in_sizes; (void)n_in; (void)out_size; (void)d_ws; (void)ws_size;
    const float* points = (const float*)d_in[0];
    const float* Wd     = (const float*)d_in[1];
    const float* bd     = (const float*)d_in[2];
    const float* Wa     = (const float*)d_in[3];
    const float* ba     = (const float*)d_in[4];
    float* out = (float*)d_out;

    prep_kernel<<<N_PTS, 64, 0, stream>>>(points, Wd, Wa);

    dim3 grid(N_PTS / MT, N_PTS);
    main_kernel<<<grid, NTHREADS, 0, stream>>>(points, bd, ba, out);
}

// Round 25
// 125.896 us; speedup vs baseline: 1.1652x; 1.1652x over previous
//
#include <hip/hip_runtime.h>
#include <math.h>

#define N_PTS 512
#define HID 128
#define KNN 8
#define MT 16               // m-tile per block
#define NTHREADS 512        // 8 waves: kset = w>>2 (KNN half), gp = w&3 (g-pair)
#define NROWS 144           // 16 d rows + 128 a rows (8k x 16m)

typedef __attribute__((ext_vector_type(8))) short short8_t;   // 8 bf16 (4 VGPRs)
typedef __attribute__((ext_vector_type(4))) float f32x4_t;    // MFMA acc

// Persistent scratch in static device globals.
__device__ float g_refv[N_PTS * KNN * 3];          // [n][k][xyz] neighbor ref vectors
__device__ unsigned short g_wfrag[2 * 8 * 4 * 64 * 8]; // [sel][gtile][ktile][lane][j] bf16 B-frags

__device__ __forceinline__ unsigned short f2bf(float f) {   // RNE f32->bf16
    const unsigned int u = __float_as_uint(f);
    return (unsigned short)((u + 0x7FFFu + ((u >> 16) & 1u)) >> 16);
}

// -------- prep: fused wave-kNN + wfrag (VERBATIM r18/r19/r22-PASS) ----------
__global__ void __launch_bounds__(64) prep_kernel(
    const float* __restrict__ points, const float* __restrict__ Wd,
    const float* __restrict__ Wa)
{
    __shared__ float spts[N_PTS * 3];
    const int lane = threadIdx.x;       // 0..63
    const int n = blockIdx.x;           // 0..511

    for (int i = lane; i < N_PTS * 3; i += 64) spts[i] = points[i];
    __syncthreads();

    {
        const int idx = n * 64 + lane;
        const int sel = idx >> 14;          // 0 = Wd, 1 = Wa
        const int rem = idx & 16383;
        const int gg = rem >> 7, kk = rem & 127;
        const int gtile = gg >> 4, glo = gg & 15;
        const int ktile = kk >> 5, kmid = (kk >> 3) & 3, j = kk & 7;
        const int fl = kmid * 16 + glo;
        const int dst = ((((sel * 8 + gtile) * 4 + ktile) * 64) + fl) * 8 + j;
        const float v = sel ? Wa[gg * HID + kk] : Wd[gg * HID + kk];
        g_wfrag[dst] = f2bf(v);
    }

    const float px = spts[n * 3 + 0], py = spts[n * 3 + 1], pz = spts[n * 3 + 2];
    unsigned long long keys[8];
#pragma unroll
    for (int j = 0; j < 8; ++j) {
        const int m = lane * 8 + j;
        const float dx = spts[m * 3 + 0] - px;
        const float dy = spts[m * 3 + 1] - py;
        const float dz = spts[m * 3 + 2] - pz;
        const float sq = dx * dx + dy * dy + dz * dz;
        keys[j] = ((unsigned long long)__float_as_uint(sq) << 32) | (unsigned)m;
    }
    for (int r = 0; r < 9; ++r) {
        unsigned long long lmin = ~0ULL;
#pragma unroll
        for (int j = 0; j < 8; ++j) lmin = keys[j] < lmin ? keys[j] : lmin;
        for (int s = 1; s < 64; s <<= 1) {
            const unsigned long long o = __shfl_xor(lmin, s, 64);
            lmin = o < lmin ? o : lmin;
        }
        const int mwin = (int)(unsigned)lmin;
        if ((mwin >> 3) == lane) keys[mwin & 7] = ~0ULL;
        if (r > 0 && lane == 0) {
            const int k = r - 1;
            g_refv[(n * KNN + k) * 3 + 0] = __fsub_rn(spts[mwin * 3 + 0], px);
            g_refv[(n * KNN + k) * 3 + 1] = __fsub_rn(spts[mwin * 3 + 1], py);
            g_refv[(n * KNN + k) * 3 + 2] = __fsub_rn(spts[mwin * 3 + 2], pz);
        }
    }
}

// -------- main: 8 waves, k-split GEMM (kset x g-pair), 2 blocks/CU ----------
__global__ void __launch_bounds__(NTHREADS, 4) main_kernel(
    const float* __restrict__ points, const float* __restrict__ bd,
    const float* __restrict__ ba, float* __restrict__ out)
{
    __shared__ __align__(16) unsigned short sA[NROWS * HID];  // 36 KB, XOR-swizzled
    __shared__ __align__(16) float sOut[8][MT][16];           // 8 KB kset1 partial amax
    __shared__ float sBaseS[8][18];     // stripe-major: [row&7][row>>3]
    __shared__ float sRef[KNN][3];
    __shared__ float sPm[MT][3];
    __shared__ float sPn[3];

    const int t = threadIdx.x;
    const int n = blockIdx.y;
    const int m0 = blockIdx.x * MT;

    const int r0 = t >> 6;              // wave id (0..7) = fill row stripe
    const int i  = t & 63;              // lane / frequency index
    const float dv2 = expf(-0.14391156831212787f * (float)i) * 0.15915494309189535f;

    // ---- stage small data ----
    if (t < 3) sPn[t] = points[n * 3 + t];
    if (t >= 64 && t < 64 + MT * 3) { int q = t - 64;  sPm[q / 3][q % 3] = points[m0 * 3 + q]; }
    if (t >= 128 && t < 128 + KNN * 3) { int q = t - 128; sRef[q / 3][q % 3] = g_refv[n * KNN * 3 + q]; }
    __syncthreads();

    // ---- geometry (r12-validated arithmetic; row -> sBaseS[row&7][row>>3]) ----
    if (t < MT) {
        const float qx = sPm[t][0], qy = sPm[t][1], qz = sPm[t][2];
        const float sn = __fadd_rn(__fadd_rn(__fmul_rn(sPn[0], sPn[0]), __fmul_rn(sPn[1], sPn[1])), __fmul_rn(sPn[2], sPn[2]));
        const float sm = __fadd_rn(__fadd_rn(__fmul_rn(qx, qx), __fmul_rn(qy, qy)), __fmul_rn(qz, qz));
        float dot = __fmul_rn(sPn[0], qx);
        dot = fmaf(sPn[1], qy, dot);
        dot = fmaf(sPn[2], qz, dot);
        float sq = __fsub_rn(__fadd_rn(sn, sm), __fadd_rn(dot, dot));
        sq = fmaxf(sq, 0.0f);
        sBaseS[t & 7][t >> 3] = __fdiv_rn(__fsqrt_rn(sq), 0.2f);   // row = t
    }
    if (t < MT * KNN) {
        const int pair = t >> 3, k = t & 7;
        const float ax = sPm[pair][0] - sPn[0];
        const float ay = sPm[pair][1] - sPn[1];
        const float az = sPm[pair][2] - sPn[2];
        const float rx = sRef[k][0], ry = sRef[k][1], rz = sRef[k][2];
        const float cx = ry * az - rz * ay;
        const float cy = rz * ax - rx * az;
        const float cz = rx * ay - ry * ax;
        const float sv = sqrtf(cx * cx + cy * cy + cz * cz);
        const float cv = rx * ax + ry * ay + rz * az;
        float ang;
        if (sv == 0.0f) ang = 0.0f;          // degenerate -> 0, NEVER pi (r12 fix)
        else            ang = atan2f(sv, cv);
        // row = 16 + k*16 + pair: stripe = pair&7, idx = 2 + 2k + (pair>>3)
        sBaseS[pair & 7][2 + 2 * k + (pair >> 3)] = ang * 3.8197186342054885f;
    }
    __syncthreads();

    // ---- A tile fill: r18-PASS pattern (8 stripes x 18 rows) ----
    {
        const float* const rd = &sBaseS[r0][0];
        char* const wr = (char*)sA + ((unsigned)((i * 4) ^ (r0 << 4)) + (unsigned)r0 * 256);
#pragma unroll
        for (int it = 0; it < 18; ++it) {
            const float base = rd[it];                        // sBaseS[r0][it] (row r0+8it)
            const float rev0 = base * dv2;
            const float rev  = rev0 - floorf(rev0);           // v_fract
            const float s = __builtin_amdgcn_sinf(rev);
            const float c = __builtin_amdgcn_cosf(rev);
            const unsigned int pack = __builtin_amdgcn_perm(
                __float_as_uint(c), __float_as_uint(s), 0x07060302u);
            *(unsigned int*)(wr + it * 2048) = pack;          // row*256 = r0*256 + it*2048
        }
    }
    __syncthreads();

    // ---- GEMM: wave = (kset = wid>>2, gp = wid&3); g-tiles {2gp, 2gp+1} ----
    const int wid  = r0;
    const int lane = i;
    const int kset = wid >> 2;      // 0: KNN k 0..3 (+d-part), 1: KNN k 4..7
    const int gp   = wid & 3;
    const int rlo  = lane & 15;
    const int kseg = lane >> 4;

    const short8_t* wf = (const short8_t*)g_wfrag;
    short8_t wab[2][4];
#pragma unroll
    for (int gt = 0; gt < 2; ++gt) {
        const int gtile = gp * 2 + gt;
#pragma unroll
        for (int kt = 0; kt < 4; ++kt)
            wab[gt][kt] = wf[((8 + gtile) * 4 + kt) * 64 + lane];
    }

    const char* sAb = (const char*)sA;
    const f32x4_t vz = {0.f, 0.f, 0.f, 0.f};

    // a-part: this wave's 4 KNN k's
    f32x4_t amax[2] = {vz, vz};
#pragma unroll
    for (int kl = 0; kl < 4; ++kl) {
        const int kk = kset * 4 + kl;
        f32x4_t acc0 = vz, acc1 = vz;
        const int rowb = MT + kk * 16 + rlo;
#pragma unroll
        for (int kt = 0; kt < 4; ++kt) {
            int byte = rowb * 256 + kt * 64 + kseg * 16;
            byte ^= (rowb & 7) << 4;
            const short8_t af = *(const short8_t*)(sAb + byte);
            acc0 = __builtin_amdgcn_mfma_f32_16x16x32_bf16(af, wab[0][kt], acc0, 0, 0, 0);
            acc1 = __builtin_amdgcn_mfma_f32_16x16x32_bf16(af, wab[1][kt], acc1, 0, 0, 0);
        }
        if (kl == 0) { amax[0] = acc0; amax[1] = acc1; }
        else {
#pragma unroll
            for (int r = 0; r < 4; ++r) {
                amax[0][r] = fmaxf(amax[0][r], acc0[r]);
                amax[1][r] = fmaxf(amax[1][r], acc1[r]);
            }
        }
    }

    // d-part: kset0 waves only
    f32x4_t accd[2] = {vz, vz};
    if (kset == 0) {
        short8_t wdb[2][4];
#pragma unroll
        for (int gt = 0; gt < 2; ++gt) {
            const int gtile = gp * 2 + gt;
#pragma unroll
            for (int kt = 0; kt < 4; ++kt)
                wdb[gt][kt] = wf[(gtile * 4 + kt) * 64 + lane];
        }
#pragma unroll
        for (int kt = 0; kt < 4; ++kt) {
            int byte = rlo * 256 + kt * 64 + kseg * 16;
            byte ^= (rlo & 7) << 4;
            const short8_t af = *(const short8_t*)(sAb + byte);
            accd[0] = __builtin_amdgcn_mfma_f32_16x16x32_bf16(af, wdb[0][kt], accd[0], 0, 0, 0);
            accd[1] = __builtin_amdgcn_mfma_f32_16x16x32_bf16(af, wdb[1][kt], accd[1], 0, 0, 0);
        }
    } else {
        // publish kset1 partial amax
#pragma unroll
        for (int gt = 0; gt < 2; ++gt)
#pragma unroll
            for (int r = 0; r < 4; ++r)
                sOut[gp * 2 + gt][kseg * 4 + r][rlo] = amax[gt][r];
    }
    __syncthreads();

    // ---- combine + store (kset0 waves) ----
    if (kset == 0) {
#pragma unroll
        for (int gt = 0; gt < 2; ++gt) {
            const int g = (gp * 2 + gt) * 16 + rlo;
            const float bdv = bd[g];
            const float bav = ba[g];
#pragma unroll
            for (int r = 0; r < 4; ++r) {
                const int m = kseg * 4 + r;
                const float ax = fmaxf(amax[gt][r], sOut[gp * 2 + gt][m][rlo]);
                out[(n * N_PTS + (m0 + m)) * HID + g] = accd[gt][r] + bdv + ax + bav;
            }
        }
    }
}

extern "C" void kernel_launch(void* const* d_in, const int* in_sizes, int n_in,
                              void* d_out, int out_size, void* d_ws, size_t ws_size,
                              hipStream_t stream) {
    (void)in_sizes; (void)n_in; (void)out_size; (void)d_ws; (void)ws_size;
    const float* points = (const float*)d_in[0];
    const float* Wd     = (const float*)d_in[1];
    const float* bd     = (const float*)d_in[2];
    const float* Wa     = (const float*)d_in[3];
    const float* ba     = (const float*)d_in[4];
    float* out = (float*)d_out;

    prep_kernel<<<N_PTS, 64, 0, stream>>>(points, Wd, Wa);

    dim3 grid(N_PTS / MT, N_PTS);
    main_kernel<<<grid, NTHREADS, 0, stream>>>(points, bd, ba, out);
}

// Round 26
// 125.088 us; speedup vs baseline: 1.1728x; 1.0065x over previous
//
#include <hip/hip_runtime.h>
#include <math.h>

#define N_PTS 512
#define HID 128
#define KNN 8
#define MT 16               // m-tile per block
#define NTHREADS 256        // 4 waves: gset = w&1 (g-half), kset = w>>1 (k-half)
#define NROWS 144           // 16 d rows + 128 a rows (8k x 16m)

typedef __attribute__((ext_vector_type(8))) short short8_t;   // 8 bf16 (4 VGPRs)
typedef __attribute__((ext_vector_type(4))) float f32x4_t;    // MFMA acc

// Persistent scratch in static device globals.
__device__ float g_refv[N_PTS * KNN * 3];          // [n][k][xyz] neighbor ref vectors
__device__ unsigned short g_wfrag[2 * 8 * 4 * 64 * 8]; // [sel][gtile][ktile][lane][j] bf16 B-frags

__device__ __forceinline__ unsigned short f2bf(float f) {   // RNE f32->bf16
    const unsigned int u = __float_as_uint(f);
    return (unsigned short)((u + 0x7FFFu + ((u >> 16) & 1u)) >> 16);
}

// -------- prep: fused wave-kNN + wfrag (VERBATIM r18/r19/r22-PASS) ----------
__global__ void __launch_bounds__(64) prep_kernel(
    const float* __restrict__ points, const float* __restrict__ Wd,
    const float* __restrict__ Wa)
{
    __shared__ float spts[N_PTS * 3];
    const int lane = threadIdx.x;       // 0..63
    const int n = blockIdx.x;           // 0..511

    for (int i = lane; i < N_PTS * 3; i += 64) spts[i] = points[i];
    __syncthreads();

    {
        const int idx = n * 64 + lane;
        const int sel = idx >> 14;          // 0 = Wd, 1 = Wa
        const int rem = idx & 16383;
        const int gg = rem >> 7, kk = rem & 127;
        const int gtile = gg >> 4, glo = gg & 15;
        const int ktile = kk >> 5, kmid = (kk >> 3) & 3, j = kk & 7;
        const int fl = kmid * 16 + glo;
        const int dst = ((((sel * 8 + gtile) * 4 + ktile) * 64) + fl) * 8 + j;
        const float v = sel ? Wa[gg * HID + kk] : Wd[gg * HID + kk];
        g_wfrag[dst] = f2bf(v);
    }

    const float px = spts[n * 3 + 0], py = spts[n * 3 + 1], pz = spts[n * 3 + 2];
    unsigned long long keys[8];
#pragma unroll
    for (int j = 0; j < 8; ++j) {
        const int m = lane * 8 + j;
        const float dx = spts[m * 3 + 0] - px;
        const float dy = spts[m * 3 + 1] - py;
        const float dz = spts[m * 3 + 2] - pz;
        const float sq = dx * dx + dy * dy + dz * dz;
        keys[j] = ((unsigned long long)__float_as_uint(sq) << 32) | (unsigned)m;
    }
    for (int r = 0; r < 9; ++r) {
        unsigned long long lmin = ~0ULL;
#pragma unroll
        for (int j = 0; j < 8; ++j) lmin = keys[j] < lmin ? keys[j] : lmin;
        for (int s = 1; s < 64; s <<= 1) {
            const unsigned long long o = __shfl_xor(lmin, s, 64);
            lmin = o < lmin ? o : lmin;
        }
        const int mwin = (int)(unsigned)lmin;
        if ((mwin >> 3) == lane) keys[mwin & 7] = ~0ULL;
        if (r > 0 && lane == 0) {
            const int k = r - 1;
            g_refv[(n * KNN + k) * 3 + 0] = __fsub_rn(spts[mwin * 3 + 0], px);
            g_refv[(n * KNN + k) * 3 + 1] = __fsub_rn(spts[mwin * 3 + 1], py);
            g_refv[(n * KNN + k) * 3 + 2] = __fsub_rn(spts[mwin * 3 + 2], pz);
        }
    }
}

// -------- main: r22 fill + (gset x kset) GEMM partition, A-reads 160->72 ----
__global__ void __launch_bounds__(NTHREADS, 3) main_kernel(
    const float* __restrict__ points, const float* __restrict__ bd,
    const float* __restrict__ ba, float* __restrict__ out)
{
    __shared__ __align__(16) unsigned short sA[NROWS * HID];  // 36 KB, XOR-swizzled
    __shared__ __align__(16) float sOutP[8][MT][17];          // kset1 partial amax (pad 17)
    __shared__ __align__(16) float sBaseS[4][36];  // stripe-major: [row&3][row>>2]
    __shared__ float sRef[KNN][3];
    __shared__ float sPm[MT][3];
    __shared__ float sPn[3];

    const int t = threadIdx.x;
    const int n = blockIdx.y;
    const int m0 = blockIdx.x * MT;

    const int r0 = t >> 6;              // wave id (0..3) = fill row stripe
    const int i  = t & 63;              // lane / frequency index
    const float dv2 = expf(-0.14391156831212787f * (float)i) * 0.15915494309189535f;

    // ---- stage small data ----
    if (t < 3) sPn[t] = points[n * 3 + t];
    if (t >= 64 && t < 64 + MT * 3) { int q = t - 64;  sPm[q / 3][q % 3] = points[m0 * 3 + q]; }
    if (t >= 128 && t < 128 + KNN * 3) { int q = t - 128; sRef[q / 3][q % 3] = g_refv[n * KNN * 3 + q]; }
    __syncthreads();

    // ---- geometry (r12-validated arithmetic; row -> sBaseS[row&3][row>>2]) ----
    if (t < MT) {
        const float qx = sPm[t][0], qy = sPm[t][1], qz = sPm[t][2];
        const float sn = __fadd_rn(__fadd_rn(__fmul_rn(sPn[0], sPn[0]), __fmul_rn(sPn[1], sPn[1])), __fmul_rn(sPn[2], sPn[2]));
        const float sm = __fadd_rn(__fadd_rn(__fmul_rn(qx, qx), __fmul_rn(qy, qy)), __fmul_rn(qz, qz));
        float dot = __fmul_rn(sPn[0], qx);
        dot = fmaf(sPn[1], qy, dot);
        dot = fmaf(sPn[2], qz, dot);
        float sq = __fsub_rn(__fadd_rn(sn, sm), __fadd_rn(dot, dot));
        sq = fmaxf(sq, 0.0f);
        sBaseS[t & 3][t >> 2] = __fdiv_rn(__fsqrt_rn(sq), 0.2f);   // row = t
    }
    if (t < MT * KNN) {
        const int pair = t >> 3, k = t & 7;
        const float ax = sPm[pair][0] - sPn[0];
        const float ay = sPm[pair][1] - sPn[1];
        const float az = sPm[pair][2] - sPn[2];
        const float rx = sRef[k][0], ry = sRef[k][1], rz = sRef[k][2];
        const float cx = ry * az - rz * ay;
        const float cy = rz * ax - rx * az;
        const float cz = rx * ay - ry * ax;
        const float sv = sqrtf(cx * cx + cy * cy + cz * cz);
        const float cv = rx * ax + ry * ay + rz * az;
        float ang;
        if (sv == 0.0f) ang = 0.0f;          // degenerate -> 0, NEVER pi (r12 fix)
        else            ang = atan2f(sv, cv);
        sBaseS[pair & 3][4 + 4 * k + (pair >> 2)] = ang * 3.8197186342054885f;
    }
    __syncthreads();

    // ---- A tile fill (r22 verbatim: batched bases, imm-offset writes) ----
    {
        float rbase[36];
#pragma unroll
        for (int q = 0; q < 9; ++q) {
            const float4 v = *(const float4*)&sBaseS[r0][q * 4];
            rbase[q * 4 + 0] = v.x; rbase[q * 4 + 1] = v.y;
            rbase[q * 4 + 2] = v.z; rbase[q * 4 + 3] = v.w;
        }
        const unsigned base0 = (unsigned)((i * 4) ^ (r0 << 4)) + (unsigned)r0 * 256;
        char* const wr0 = (char*)sA + base0;          // even it (row&7 == r0)
        char* const wr1 = (char*)sA + (base0 ^ 64u);  // odd it  (row&7 == r0+4)
#pragma unroll
        for (int it = 0; it < 36; ++it) {
            const float rev0 = rbase[it] * dv2;
            const float rev  = rev0 - floorf(rev0);
            const float s = __builtin_amdgcn_sinf(rev);
            const float c = __builtin_amdgcn_cosf(rev);
            const unsigned int pack = __builtin_amdgcn_perm(
                __float_as_uint(c), __float_as_uint(s), 0x07060302u);
            char* const wp = (it & 1) ? wr1 : wr0;
            *(unsigned int*)(wp + it * 1024) = pack;
        }
    }
    __syncthreads();

    // ---- GEMM: wave = (gset = w&1, kset = w>>1); 4 g-tiles per wave --------
    const int wid  = r0;
    const int lane = i;
    const int gset = wid & 1;       // g-tiles gset*4 .. gset*4+3
    const int kset = wid >> 1;      // a-k 0..3 (+d) or 4..7
    const int rlo  = lane & 15;
    const int kseg = lane >> 4;

    const short8_t* wf = (const short8_t*)g_wfrag;
    const char* sAb = (const char*)sA;
    const f32x4_t vz = {0.f, 0.f, 0.f, 0.f};

    // d-part first on kset0 waves (wdb scoped so it releases before wab loads)
    f32x4_t accd[4] = {vz, vz, vz, vz};
    if (kset == 0) {
        short8_t wdb[4][4];
#pragma unroll
        for (int gt = 0; gt < 4; ++gt) {
            const int gtile = gset * 4 + gt;
#pragma unroll
            for (int kt = 0; kt < 4; ++kt)
                wdb[gt][kt] = wf[(gtile * 4 + kt) * 64 + lane];
        }
#pragma unroll
        for (int kt = 0; kt < 4; ++kt) {
            int byte = rlo * 256 + kt * 64 + kseg * 16;
            byte ^= (rlo & 7) << 4;
            const short8_t af = *(const short8_t*)(sAb + byte);
#pragma unroll
            for (int gt = 0; gt < 4; ++gt)
                accd[gt] = __builtin_amdgcn_mfma_f32_16x16x32_bf16(af, wdb[gt][kt], accd[gt], 0, 0, 0);
        }
    }

    // a-part: 4 k's x 4 g-tiles; each A-read feeds 4 MFMAs
    short8_t wab[4][4];
#pragma unroll
    for (int gt = 0; gt < 4; ++gt) {
        const int gtile = gset * 4 + gt;
#pragma unroll
        for (int kt = 0; kt < 4; ++kt)
            wab[gt][kt] = wf[((8 + gtile) * 4 + kt) * 64 + lane];
    }
    f32x4_t amax[4] = {vz, vz, vz, vz};
#pragma unroll
    for (int kl = 0; kl < 4; ++kl) {
        const int kk = kset * 4 + kl;
        const int rowb = MT + kk * 16 + rlo;
        f32x4_t acc[4] = {vz, vz, vz, vz};
#pragma unroll
        for (int kt = 0; kt < 4; ++kt) {
            int byte = rowb * 256 + kt * 64 + kseg * 16;
            byte ^= (rowb & 7) << 4;
            const short8_t af = *(const short8_t*)(sAb + byte);
#pragma unroll
            for (int gt = 0; gt < 4; ++gt)
                acc[gt] = __builtin_amdgcn_mfma_f32_16x16x32_bf16(af, wab[gt][kt], acc[gt], 0, 0, 0);
        }
        if (kl == 0) {
#pragma unroll
            for (int gt = 0; gt < 4; ++gt) amax[gt] = acc[gt];
        } else {
#pragma unroll
            for (int gt = 0; gt < 4; ++gt)
#pragma unroll
                for (int r = 0; r < 4; ++r)
                    amax[gt][r] = fmaxf(amax[gt][r], acc[gt][r]);
        }
    }

    // kset1 publishes its partial amax
    if (kset == 1) {
#pragma unroll
        for (int gt = 0; gt < 4; ++gt)
#pragma unroll
            for (int r = 0; r < 4; ++r)
                sOutP[gset * 4 + gt][kseg * 4 + r][rlo] = amax[gt][r];
    }
    __syncthreads();

    // ---- combine + store (kset0 waves): col=lane&15 (g), row=kseg*4+reg (m) -
    if (kset == 0) {
#pragma unroll
        for (int gt = 0; gt < 4; ++gt) {
            const int g = (gset * 4 + gt) * 16 + rlo;
            const float bdv = bd[g];
            const float bav = ba[g];
#pragma unroll
            for (int r = 0; r < 4; ++r) {
                const int m = kseg * 4 + r;
                const float ax = fmaxf(amax[gt][r], sOutP[gset * 4 + gt][m][rlo]);
                out[(n * N_PTS + (m0 + m)) * HID + g] = accd[gt][r] + bdv + ax + bav;
            }
        }
    }
}

extern "C" void kernel_launch(void* const* d_in, const int* in_sizes, int n_in,
                              void* d_out, int out_size, void* d_ws, size_t ws_size,
                              hipStream_t stream) {
    (void)in_sizes; (void)n_in; (void)out_size; (void)d_ws; (void)ws_size;
    const float* points = (const float*)d_in[0];
    const float* Wd     = (const float*)d_in[1];
    const float* bd     = (const float*)d_in[2];
    const float* Wa     = (const float*)d_in[3];
    const float* ba     = (const float*)d_in[4];
    float* out = (float*)d_out;

    prep_kernel<<<N_PTS, 64, 0, stream>>>(points, Wd, Wa);

    dim3 grid(N_PTS / MT, N_PTS);
    main_kernel<<<grid, NTHREADS, 0, stream>>>(points, bd, ba, out);
}

// Round 27
// 108.253 us; speedup vs baseline: 1.3551x; 1.1555x over previous
//
#include <hip/hip_runtime.h>
#include <math.h>

#define N_PTS 512
#define HID 128
#define KNN 8
#define MT 16               // m's per tile
#define NTILES 4            // tiles per block (pipelined)
#define NTHREADS 256        // 4 waves; each wave covers 2 g-tiles
#define NROWS 144           // 16 d rows + 128 a rows per tile

typedef __attribute__((ext_vector_type(8))) short short8_t;   // 8 bf16 (4 VGPRs)
typedef __attribute__((ext_vector_type(4))) float f32x4_t;    // MFMA acc

__device__ float g_refv[N_PTS * KNN * 3];          // [n][k][xyz] neighbor ref vectors
__device__ unsigned short g_wfrag[2 * 8 * 4 * 64 * 8]; // [sel][gtile][ktile][lane][j] bf16 B-frags

__device__ __forceinline__ unsigned short f2bf(float f) {   // RNE f32->bf16
    const unsigned int u = __float_as_uint(f);
    return (unsigned short)((u + 0x7FFFu + ((u >> 16) & 1u)) >> 16);
}

// -------- prep: fused wave-kNN + wfrag (VERBATIM r18/r19/r22-PASS) ----------
__global__ void __launch_bounds__(64) prep_kernel(
    const float* __restrict__ points, const float* __restrict__ Wd,
    const float* __restrict__ Wa)
{
    __shared__ float spts[N_PTS * 3];
    const int lane = threadIdx.x;       // 0..63
    const int n = blockIdx.x;           // 0..511

    for (int i = lane; i < N_PTS * 3; i += 64) spts[i] = points[i];
    __syncthreads();

    {
        const int idx = n * 64 + lane;
        const int sel = idx >> 14;          // 0 = Wd, 1 = Wa
        const int rem = idx & 16383;
        const int gg = rem >> 7, kk = rem & 127;
        const int gtile = gg >> 4, glo = gg & 15;
        const int ktile = kk >> 5, kmid = (kk >> 3) & 3, j = kk & 7;
        const int fl = kmid * 16 + glo;
        const int dst = ((((sel * 8 + gtile) * 4 + ktile) * 64) + fl) * 8 + j;
        const float v = sel ? Wa[gg * HID + kk] : Wd[gg * HID + kk];
        g_wfrag[dst] = f2bf(v);
    }

    const float px = spts[n * 3 + 0], py = spts[n * 3 + 1], pz = spts[n * 3 + 2];
    unsigned long long keys[8];
#pragma unroll
    for (int j = 0; j < 8; ++j) {
        const int m = lane * 8 + j;
        const float dx = spts[m * 3 + 0] - px;
        const float dy = spts[m * 3 + 1] - py;
        const float dz = spts[m * 3 + 2] - pz;
        const float sq = dx * dx + dy * dy + dz * dz;
        keys[j] = ((unsigned long long)__float_as_uint(sq) << 32) | (unsigned)m;
    }
    for (int r = 0; r < 9; ++r) {
        unsigned long long lmin = ~0ULL;
#pragma unroll
        for (int j = 0; j < 8; ++j) lmin = keys[j] < lmin ? keys[j] : lmin;
        for (int s = 1; s < 64; s <<= 1) {
            const unsigned long long o = __shfl_xor(lmin, s, 64);
            lmin = o < lmin ? o : lmin;
        }
        const int mwin = (int)(unsigned)lmin;
        if ((mwin >> 3) == lane) keys[mwin & 7] = ~0ULL;
        if (r > 0 && lane == 0) {
            const int k = r - 1;
            g_refv[(n * KNN + k) * 3 + 0] = __fsub_rn(spts[mwin * 3 + 0], px);
            g_refv[(n * KNN + k) * 3 + 1] = __fsub_rn(spts[mwin * 3 + 1], py);
            g_refv[(n * KNN + k) * 3 + 2] = __fsub_rn(spts[mwin * 3 + 2], pz);
        }
    }
}

// -------- main: 4-tile pipeline, dbuf LDS, fused fill(t+1) || gemm(t) -------
__global__ void __launch_bounds__(NTHREADS, 2) main_kernel(
    const float* __restrict__ points, const float* __restrict__ bd,
    const float* __restrict__ ba, float* __restrict__ out)
{
    __shared__ __align__(16) unsigned short sA[2][NROWS * HID];  // 2 x 36 KB
    __shared__ __align__(16) float sBaseS[NTILES][4][36];  // stripe-major bases
    __shared__ float sRef[KNN][3];
    __shared__ float sPm[MT * NTILES][3];
    __shared__ float sPn[3];

    const int t = threadIdx.x;
    const int n = blockIdx.y;
    const int M0 = blockIdx.x * (MT * NTILES);

    const int r0 = t >> 6;              // wave id (0..3) = row stripe
    const int i  = t & 63;              // frequency index (= lane)
    const float dv2 = expf(-0.14391156831212787f * (float)i) * 0.15915494309189535f;

    // B-frags hoisted: LDS caps occupancy at 2 blocks/CU, so VGPRs are free
    const int wid = r0, lane = i;
    const short8_t* wf = (const short8_t*)g_wfrag;
    short8_t wdb[2][4], wab[2][4];
#pragma unroll
    for (int gt = 0; gt < 2; ++gt) {
        const int gtile = wid * 2 + gt;
#pragma unroll
        for (int kt = 0; kt < 4; ++kt) {
            wdb[gt][kt] = wf[(gtile * 4 + kt) * 64 + lane];
            wab[gt][kt] = wf[((8 + gtile) * 4 + kt) * 64 + lane];
        }
    }

    // ---- stage small data ----
    if (t < 3) sPn[t] = points[n * 3 + t];
    if (t >= 8 && t < 8 + KNN * 3) { int q = t - 8; sRef[q / 3][q % 3] = g_refv[n * KNN * 3 + q]; }
    if (t >= 64 && t < 64 + MT * NTILES * 3) { int q = t - 64; sPm[q / 3][q % 3] = points[M0 * 3 + q]; }
    __syncthreads();

    // ---- geometry for ALL tiles (r12-validated arithmetic) ----
    if (t < MT * NTILES) {              // 64 d-indices; t = tt*16 + pair
        const int tt = t >> 4, pair = t & 15;
        const float qx = sPm[t][0], qy = sPm[t][1], qz = sPm[t][2];
        const float sn = __fadd_rn(__fadd_rn(__fmul_rn(sPn[0], sPn[0]), __fmul_rn(sPn[1], sPn[1])), __fmul_rn(sPn[2], sPn[2]));
        const float sm = __fadd_rn(__fadd_rn(__fmul_rn(qx, qx), __fmul_rn(qy, qy)), __fmul_rn(qz, qz));
        float dot = __fmul_rn(sPn[0], qx);
        dot = fmaf(sPn[1], qy, dot);
        dot = fmaf(sPn[2], qz, dot);
        float sq = __fsub_rn(__fadd_rn(sn, sm), __fadd_rn(dot, dot));
        sq = fmaxf(sq, 0.0f);
        sBaseS[tt][pair & 3][pair >> 2] = __fdiv_rn(__fsqrt_rn(sq), 0.2f);
    }
#pragma unroll
    for (int q2 = 0; q2 < 2; ++q2) {    // 512 a-indices, 2 per thread
        const int idx = q2 * 256 + t;
        const int tt = idx >> 7, rem = idx & 127, pair = rem >> 3, k = rem & 7;
        const int mp = tt * MT + pair;
        const float ax = sPm[mp][0] - sPn[0];
        const float ay = sPm[mp][1] - sPn[1];
        const float az = sPm[mp][2] - sPn[2];
        const float rx = sRef[k][0], ry = sRef[k][1], rz = sRef[k][2];
        const float cx = ry * az - rz * ay;
        const float cy = rz * ax - rx * az;
        const float cz = rx * ay - ry * ax;
        const float sv = sqrtf(cx * cx + cy * cy + cz * cz);
        const float cv = rx * ax + ry * ay + rz * az;
        float ang;
        if (sv == 0.0f) ang = 0.0f;          // degenerate -> 0, NEVER pi (r12 fix)
        else            ang = atan2f(sv, cv);
        sBaseS[tt][pair & 3][4 + 4 * k + (pair >> 2)] = ang * 3.8197186342054885f;
    }
    __syncthreads();

    const unsigned base0 = (unsigned)((i * 4) ^ (r0 << 4)) + (unsigned)r0 * 256;
    const int rlo  = lane & 15;
    const int kseg = lane >> 4;

    // ---- prologue: fill tile 0 into sA[0] (r22 fill, verbatim values) ----
    {
        float rbase[36];
#pragma unroll
        for (int q = 0; q < 9; ++q) {
            const float4 v = *(const float4*)&sBaseS[0][r0][q * 4];
            rbase[q * 4 + 0] = v.x; rbase[q * 4 + 1] = v.y;
            rbase[q * 4 + 2] = v.z; rbase[q * 4 + 3] = v.w;
        }
        char* const wr0 = (char*)sA[0] + base0;
        char* const wr1 = (char*)sA[0] + (base0 ^ 64u);
#pragma unroll
        for (int it = 0; it < 36; ++it) {
            const float rev0 = rbase[it] * dv2;
            const float rev  = rev0 - floorf(rev0);
            const float s = __builtin_amdgcn_sinf(rev);
            const float c = __builtin_amdgcn_cosf(rev);
            const unsigned int pack = __builtin_amdgcn_perm(
                __float_as_uint(c), __float_as_uint(s), 0x07060302u);
            char* const wp = (it & 1) ? wr1 : wr0;
            *(unsigned int*)(wp + it * 1024) = pack;
        }
    }
    __syncthreads();

    // ---- phases: gemm(tile tt from sA[tt&1]) fused with fill(tt+1 -> sA[~tt&1]) ----
    const f32x4_t vz = {0.f, 0.f, 0.f, 0.f};
#pragma unroll
    for (int tt = 0; tt < NTILES; ++tt) {
        const char* sAb = (const char*)sA[tt & 1];
        const bool dofill = (tt < NTILES - 1);

        float rbase[36];
        char* wr0 = (char*)sA[(tt + 1) & 1] + base0;
        char* wr1 = (char*)sA[(tt + 1) & 1] + (base0 ^ 64u);
        if (dofill) {
#pragma unroll
            for (int q = 0; q < 9; ++q) {
                const float4 v = *(const float4*)&sBaseS[tt + 1][r0][q * 4];
                rbase[q * 4 + 0] = v.x; rbase[q * 4 + 1] = v.y;
                rbase[q * 4 + 2] = v.z; rbase[q * 4 + 3] = v.w;
            }
        }

        f32x4_t accd[2] = {vz, vz};
        f32x4_t amax[2] = {vz, vz};
        f32x4_t acc0 = vz, acc1 = vz;

#pragma unroll
        for (int it = 0; it < 36; ++it) {
            // --- fill one element of tile tt+1 (VALU + trans pipe) ---
            if (dofill) {
                const float rev0 = rbase[it] * dv2;
                const float rev  = rev0 - floorf(rev0);
                const float s = __builtin_amdgcn_sinf(rev);
                const float c = __builtin_amdgcn_cosf(rev);
                const unsigned int pack = __builtin_amdgcn_perm(
                    __float_as_uint(c), __float_as_uint(s), 0x07060302u);
                char* const wp = (it & 1) ? wr1 : wr0;
                *(unsigned int*)(wp + it * 1024) = pack;
            }
            // --- 2 MFMAs of tile tt (MFMA pipe) ---
            if (it < 4) {
                const int kt = it;
                int byte = rlo * 256 + kt * 64 + kseg * 16;
                byte ^= (rlo & 7) << 4;
                const short8_t af = *(const short8_t*)(sAb + byte);
                accd[0] = __builtin_amdgcn_mfma_f32_16x16x32_bf16(af, wdb[0][kt], accd[0], 0, 0, 0);
                accd[1] = __builtin_amdgcn_mfma_f32_16x16x32_bf16(af, wdb[1][kt], accd[1], 0, 0, 0);
            } else {
                const int q = it - 4, k = q >> 2, kt = q & 3;
                const int rowb = MT + k * 16 + rlo;
                int byte = rowb * 256 + kt * 64 + kseg * 16;
                byte ^= (rowb & 7) << 4;
                const short8_t af = *(const short8_t*)(sAb + byte);
                acc0 = __builtin_amdgcn_mfma_f32_16x16x32_bf16(af, wab[0][kt], acc0, 0, 0, 0);
                acc1 = __builtin_amdgcn_mfma_f32_16x16x32_bf16(af, wab[1][kt], acc1, 0, 0, 0);
                if (kt == 3) {
                    if (k == 0) { amax[0] = acc0; amax[1] = acc1; }
                    else {
#pragma unroll
                        for (int r = 0; r < 4; ++r) {
                            amax[0][r] = fmaxf(amax[0][r], acc0[r]);
                            amax[1][r] = fmaxf(amax[1][r], acc1[r]);
                        }
                    }
                    acc0 = vz; acc1 = vz;
                }
            }
        }

        // ---- epilogue for tile tt ----
#pragma unroll
        for (int gt = 0; gt < 2; ++gt) {
            const int g = (wid * 2 + gt) * 16 + rlo;
            const float bdv = bd[g];
            const float bav = ba[g];
#pragma unroll
            for (int r = 0; r < 4; ++r) {
                const int m = M0 + tt * MT + kseg * 4 + r;
                out[(n * N_PTS + m) * HID + g] = accd[gt][r] + bdv + amax[gt][r] + bav;
            }
        }
        __syncthreads();
    }
}

extern "C" void kernel_launch(void* const* d_in, const int* in_sizes, int n_in,
                              void* d_out, int out_size, void* d_ws, size_t ws_size,
                              hipStream_t stream) {
    (void)in_sizes; (void)n_in; (void)out_size; (void)d_ws; (void)ws_size;
    const float* points = (const float*)d_in[0];
    const float* Wd     = (const float*)d_in[1];
    const float* bd     = (const float*)d_in[2];
    const float* Wa     = (const float*)d_in[3];
    const float* ba     = (const float*)d_in[4];
    float* out = (float*)d_out;

    prep_kernel<<<N_PTS, 64, 0, stream>>>(points, Wd, Wa);

    dim3 grid(N_PTS / (MT * NTILES), N_PTS);
    main_kernel<<<grid, NTHREADS, 0, stream>>>(points, bd, ba, out);
}